// Round 1
// baseline (351.277 us; speedup 1.0000x reference)
//
#include <hip/hip_runtime.h>

#define N_RAYS    131072
#define N_SAMPLES 128
#define FAR_DELTA 1e10f

// One 64-lane wave per ray; each lane owns samples s0=2*lane, s1=2*lane+1.
// Cumprod via wave-wide shuffle scan; weighted sums via butterfly reduction.
__global__ __launch_bounds__(256) void VolumeRenderer_57612691308835_kernel(
    const float* __restrict__ density,      // [N, S]
    const float* __restrict__ feature,      // [N, S, 3]
    const float* __restrict__ depth,        // [N, S]
    float* __restrict__ out_feat,           // [N, 3]
    float* __restrict__ out_depth)          // [N]
{
    const int wave = threadIdx.x >> 6;
    const int lane = threadIdx.x & 63;
    const int ray  = (blockIdx.x << 2) + wave;   // 4 rays per 256-thread block
    if (ray >= N_RAYS) return;

    const int  s0   = lane << 1;
    const long base = (long)ray * N_SAMPLES;

    // Coalesced vector loads: 8B density + 8B depth + 24B feature per lane.
    const float2 den = *(const float2*)(density + base + s0);
    const float2 dep = *(const float2*)(depth   + base + s0);
    const float* fp  = feature + (base + s0) * 3;
    const float2 f01 = *(const float2*)(fp);       // s0: x,y
    const float2 f23 = *(const float2*)(fp + 2);   // s0: z | s1: x
    const float2 f45 = *(const float2*)(fp + 4);   // s1: y,z

    // deltas: depth[s+1]-depth[s]; last sample gets FAR_DELTA sentinel.
    const float d_next = __shfl_down(dep.x, 1);    // depth[s0+2] from lane+1
    const float delta0 = dep.y - dep.x;
    const float delta1 = (lane == 63) ? FAR_DELTA : (d_next - dep.y);

    const float att0 = __expf(-den.x * delta0);
    const float att1 = __expf(-den.y * delta1);

    // Inclusive product-scan across the wave of per-lane pair products.
    float scan = att0 * att1;
    #pragma unroll
    for (int off = 1; off < 64; off <<= 1) {
        const float v = __shfl_up(scan, off);
        scan *= (lane >= off) ? v : 1.0f;
    }
    // Exclusive prefix (product of all samples before s0).
    float excl = __shfl_up(scan, 1);
    if (lane == 0) excl = 1.0f;

    const float T0 = excl * att0;     // inclusive T at s0
    const float T1 = T0   * att1;     // inclusive T at s1
    const float w0 = T0 * (1.0f - att0);
    const float w1 = T1 * (1.0f - att1);

    float fx = w0 * f01.x + w1 * f23.y;
    float fy = w0 * f01.y + w1 * f45.x;
    float fz = w0 * f23.x + w1 * f45.y;
    float dd = w0 * dep.x + w1 * dep.y;

    // Wave-wide butterfly sum of the 4 accumulators.
    #pragma unroll
    for (int off = 32; off >= 1; off >>= 1) {
        fx += __shfl_xor(fx, off);
        fy += __shfl_xor(fy, off);
        fz += __shfl_xor(fz, off);
        dd += __shfl_xor(dd, off);
    }

    if (lane == 0) {
        out_feat[ray * 3 + 0] = fx;
        out_feat[ray * 3 + 1] = fy;
        out_feat[ray * 3 + 2] = fz;
        out_depth[ray]        = dd;
    }
}

extern "C" void kernel_launch(void* const* d_in, const int* in_sizes, int n_in,
                              void* d_out, int out_size, void* d_ws, size_t ws_size,
                              hipStream_t stream) {
    const float* density = (const float*)d_in[0];   // [N, S]
    const float* feature = (const float*)d_in[1];   // [N, S, 3]
    const float* depth   = (const float*)d_in[2];   // [N, S]

    float* out_feat  = (float*)d_out;                       // [N, 3] flat first
    float* out_depth = (float*)d_out + (long)N_RAYS * 3;    // [N] after

    const int rays_per_block = 4;                    // 256 threads / 64
    const int grid = N_RAYS / rays_per_block;        // 32768
    VolumeRenderer_57612691308835_kernel<<<grid, 256, 0, stream>>>(
        density, feature, depth, out_feat, out_depth);
}